// Round 15
// baseline (300.765 us; speedup 1.0000x reference)
//
#include <hip/hip_runtime.h>
#include <hip/hip_bf16.h>

#define N_NODES 50000
#define N_EDGES 800000
#define NNZ_H   800000
#define M_HE    10000
#define F_IN    128
#define F_HID   64

// coarse-bucket geometry for the two-level counting sort
#define SH_E 7
#define NB_E ((N_NODES + 127) >> 7)     // 391
#define SH_H 5
#define NB_H ((M_HE + 31) >> 5)         // 313
#define SH_N 7
#define NB_N ((N_NODES + 127) >> 7)     // 391
#define TILE 4096
#define GB   ((N_EDGES + TILE - 1) / TILE)   // 196 (E == NNZ)
#define NBMAX 400
#define KPBMAX 128
#define GG  782     // (N_NODES+63)/64 GEMM blocks
#define GWN 12500   // N_NODES/4 wave-per-node blocks

typedef float nf2 __attribute__((ext_vector_type(2)));   // clang-native float2 for NT stores

static __device__ __forceinline__ float bflo(unsigned v) { return __uint_as_float(v << 16); }
static __device__ __forceinline__ float bfhi(unsigned v) { return __uint_as_float(v & 0xFFFF0000u); }
#define NTL(p) __builtin_nontemporal_load(p)
static __device__ __forceinline__ void nts2(float* p, float x, float y) {
    nf2 v; v.x = x; v.y = y;
    __builtin_nontemporal_store(v, (nf2*)p);
}

// ---------------- pass A: fused bucket histograms (int2 reads) ----------------
__global__ void k_hist_all(const int* __restrict__ e_col, const int* __restrict__ h_idx,
                           const int* __restrict__ n_idx,
                           int* __restrict__ bcntE, int* __restrict__ bcntH, int* __restrict__ bcntN) {
    __shared__ int hE[NB_E], hH[NB_H], hN[NB_N];
    for (int i = threadIdx.x; i < NB_E; i += 256) hE[i] = 0;
    for (int i = threadIdx.x; i < NB_H; i += 256) hH[i] = 0;
    for (int i = threadIdx.x; i < NB_N; i += 256) hN[i] = 0;
    __syncthreads();
    const int2* ec2 = (const int2*)e_col;
    const int2* hi2 = (const int2*)h_idx;
    const int2* ni2 = (const int2*)n_idx;
    int stride = gridDim.x * 256;
    for (int i = blockIdx.x * 256 + threadIdx.x; i < N_EDGES / 2; i += stride) {
        int2 e = ec2[i];
        atomicAdd(&hE[e.x >> SH_E], 1);
        atomicAdd(&hE[e.y >> SH_E], 1);
        int2 hh = hi2[i];
        atomicAdd(&hH[hh.x >> SH_H], 1);
        atomicAdd(&hH[hh.y >> SH_H], 1);
        int2 nn = ni2[i];
        atomicAdd(&hN[nn.x >> SH_N], 1);
        atomicAdd(&hN[nn.y >> SH_N], 1);
    }
    __syncthreads();
    for (int i = threadIdx.x; i < NB_E; i += 256) if (hE[i]) atomicAdd(&bcntE[i], hE[i]);
    for (int i = threadIdx.x; i < NB_H; i += 256) if (hH[i]) atomicAdd(&bcntH[i], hH[i]);
    for (int i = threadIdx.x; i < NB_N; i += 256) if (hN[i]) atomicAdd(&bcntN[i], hN[i]);
}

// ---------------- in-LDS exclusive scan of bcnt[0..nb) (nb <= 512), 256 threads ----------------
__device__ void scan_to_lds(const int* __restrict__ in, int* __restrict__ soff, int nb,
                            int* __restrict__ tsum) {
    int t = threadIdx.x;
    int v0 = (2 * t < nb) ? in[2 * t] : 0;
    int v1 = (2 * t + 1 < nb) ? in[2 * t + 1] : 0;
    tsum[t] = v0 + v1;
    __syncthreads();
    for (int d = 1; d < 256; d <<= 1) {
        int u = (t >= d) ? tsum[t - d] : 0;
        __syncthreads();
        tsum[t] += u;
        __syncthreads();
    }
    int run = (t > 0) ? tsum[t - 1] : 0;
    if (2 * t < nb) soff[2 * t] = run;
    if (2 * t + 1 < nb) soff[2 * t + 1] = run + v0;
    __syncthreads();
}

// ---------------- pass B: chunked scatter, packed payload, self-scanned offsets ----------------
__device__ void chunk_scatter(const int* __restrict__ keys, const int* __restrict__ vals,
                              int n, int sh, int nb,
                              const int* __restrict__ bcnt, int* __restrict__ bcur,
                              int* __restrict__ bk, int blk) {
    __shared__ int h[NBMAX], loc[NBMAX], base[NBMAX], hc[NBMAX], soff[NBMAX];
    __shared__ int tsum[256];
    __shared__ int buf[TILE];
    __shared__ unsigned short bkt[TILE];
    scan_to_lds(bcnt, soff, nb, tsum);
    int t0 = blk * TILE;
    int tend = min(t0 + TILE, n);
    int cnt = tend - t0;
    for (int b = threadIdx.x; b < nb; b += 256) { h[b] = 0; hc[b] = 0; }
    __syncthreads();
    for (int i = t0 + threadIdx.x; i < tend; i += 256)
        atomicAdd(&h[keys[i] >> sh], 1);
    __syncthreads();
    if (threadIdx.x == 0) {
        int run = 0;
        for (int b = 0; b < nb; ++b) { loc[b] = run; run += h[b]; }
    }
    __syncthreads();
    for (int b = threadIdx.x; b < nb; b += 256)
        base[b] = soff[b] + atomicAdd(&bcur[b], h[b]);
    __syncthreads();
    for (int i = t0 + threadIdx.x; i < tend; i += 256) {
        int k = keys[i];
        int b = k >> sh;
        int r = loc[b] + atomicAdd(&hc[b], 1);
        buf[r] = ((k - (b << sh)) << 16) | vals[i];
        bkt[r] = (unsigned short)b;
    }
    __syncthreads();
    for (int j = threadIdx.x; j < cnt; j += 256) {
        int b = bkt[j];
        bk[base[b] + (j - loc[b])] = buf[j];
    }
}
__global__ void k_chunk_all(const int* __restrict__ e_row, const int* __restrict__ e_col,
                            const int* __restrict__ n_idx, const int* __restrict__ h_idx,
                            const int* __restrict__ bcntE, int* __restrict__ bcurE, int* __restrict__ bkE,
                            const int* __restrict__ bcntH, int* __restrict__ bcurH, int* __restrict__ bkH,
                            const int* __restrict__ bcntN, int* __restrict__ bcurN, int* __restrict__ bkN) {
    int gb = blockIdx.x;
    if (gb < GB)            chunk_scatter(e_col, e_row, N_EDGES, SH_E, NB_E, bcntE, bcurE, bkE, gb);
    else if (gb < 2 * GB)   chunk_scatter(h_idx, n_idx, NNZ_H,  SH_H, NB_H, bcntH, bcurH, bkH, gb - GB);
    else                    chunk_scatter(n_idx, h_idx, NNZ_H,  SH_N, NB_N, bcntN, bcurN, bkN, gb - 2 * GB);
}

// ---------------- pass C: per-bucket CSR finalize, self-scanned offsets ----------------
__global__ void k_fin_all(const int* __restrict__ bkE, const int* __restrict__ bcntE,
                          int* __restrict__ srtE, int* __restrict__ offE,
                          const int* __restrict__ bkH, const int* __restrict__ bcntH,
                          int* __restrict__ srtH, int* __restrict__ offH,
                          const int* __restrict__ bkN, const int* __restrict__ bcntN,
                          int* __restrict__ srtN, int* __restrict__ offN) {
    __shared__ int koff[KPBMAX];
    __shared__ int kcur[KPBMAX];
    __shared__ int tsum[256];
    __shared__ int soff[NBMAX];
    int b = blockIdx.x;
    const int* bk; const int* bcnt; int* srt; int* off;
    int nb, sh, nkeys, total;
    if (b < NB_E) {
        bk = bkE; bcnt = bcntE; srt = srtE; off = offE;
        nb = NB_E; sh = SH_E; nkeys = N_NODES; total = N_EDGES;
    } else if (b < NB_E + NB_H) {
        b -= NB_E;
        bk = bkH; bcnt = bcntH; srt = srtH; off = offH;
        nb = NB_H; sh = SH_H; nkeys = M_HE; total = NNZ_H;
    } else {
        b -= NB_E + NB_H;
        bk = bkN; bcnt = bcntN; srt = srtN; off = offN;
        nb = NB_N; sh = SH_N; nkeys = N_NODES; total = NNZ_H;
    }
    scan_to_lds(bcnt, soff, nb, tsum);
    int kpb = 1 << sh;
    int k0 = b << sh;
    int beg = soff[b];
    int end = (b + 1 < nb) ? soff[b + 1] : total;
    int t = threadIdx.x;
    if (t < kpb) { koff[t] = 0; kcur[t] = 0; }
    __syncthreads();
    for (int i = beg + t; i < end; i += 256)
        atomicAdd(&koff[((unsigned)bk[i]) >> 16], 1);
    __syncthreads();
    int v = (t < kpb) ? koff[t] : 0;
    tsum[t] = v;
    __syncthreads();
    for (int d = 1; d < 256; d <<= 1) {
        int u = (t >= d) ? tsum[t - d] : 0;
        __syncthreads();
        tsum[t] += u;
        __syncthreads();
    }
    if (t < kpb) koff[t] = tsum[t] - v;
    __syncthreads();
    if (t < kpb && (k0 + t) < nkeys) off[k0 + t] = beg + koff[t];
    if (b == nb - 1 && t == 0) off[nkeys] = total;
    for (int i = beg + t; i < end; i += 256) {
        int p = bk[i];
        int lk = ((unsigned)p) >> 16;
        int pos = beg + koff[lk] + atomicAdd(&kcur[lk], 1);
        srt[pos] = p & 0xFFFF;
    }
}

// ---------------- register-tiled GEMM body -> bf16 out (transposed-x LDS, b128 reads) ----------------
template<int K, bool SCALE>
__device__ __forceinline__ void gemm_body(const float* __restrict__ xin, const float* __restrict__ w,
                                          const int* __restrict__ offE, __hip_bfloat16* __restrict__ out,
                                          int blk, float* __restrict__ wl, float* __restrict__ xs) {
    int tid = threadIdx.x;
    int wv = tid >> 6, lane = tid & 63;
    int cg = lane & 15;
    int rg = lane >> 4;
    int rl = wv * 16 + rg * 4;
    int r0 = blk * 64;
    float acc[4][4] = {};
    for (int k0 = 0; k0 < K; k0 += 64) {
        {
            const float4* wsrc = (const float4*)(w + k0 * 64);
            float4* wdst = (float4*)wl;
            for (int j = tid; j < 1024; j += 256) wdst[j] = wsrc[j];
        }
        // stage x tile TRANSPOSED: xs[kk*68 + r]
        for (int p = tid; p < 1024; p += 256) {
            int r = p >> 4, c4 = p & 15;
            int row = min(r0 + r, N_NODES - 1);
            const float* src = xin + (size_t)row * K + k0 + 4 * c4;
            float v0 = NTL(src + 0);
            float v1 = NTL(src + 1);
            float v2 = NTL(src + 2);
            float v3 = NTL(src + 3);
            xs[(4 * c4 + 0) * 68 + r] = v0;
            xs[(4 * c4 + 1) * 68 + r] = v1;
            xs[(4 * c4 + 2) * 68 + r] = v2;
            xs[(4 * c4 + 3) * 68 + r] = v3;
        }
        __syncthreads();
#pragma unroll 4
        for (int kk = 0; kk < 64; ++kk) {
            float4 wf = *(const float4*)&wl[kk * 64 + cg * 4];
            float4 xf = *(const float4*)&xs[kk * 68 + rl];
            acc[0][0] += xf.x * wf.x; acc[0][1] += xf.x * wf.y; acc[0][2] += xf.x * wf.z; acc[0][3] += xf.x * wf.w;
            acc[1][0] += xf.y * wf.x; acc[1][1] += xf.y * wf.y; acc[1][2] += xf.y * wf.z; acc[1][3] += xf.y * wf.w;
            acc[2][0] += xf.z * wf.x; acc[2][1] += xf.z * wf.y; acc[2][2] += xf.z * wf.z; acc[2][3] += xf.z * wf.w;
            acc[3][0] += xf.w * wf.x; acc[3][1] += xf.w * wf.y; acc[3][2] += xf.w * wf.z; acc[3][3] += xf.w * wf.w;
        }
        __syncthreads();
    }
#pragma unroll
    for (int i = 0; i < 4; ++i) {
        int row = r0 + rl + i;
        if (row < N_NODES) {
            float s = 1.0f;
            if (SCALE) {
                float deg = (float)(offE[row + 1] - offE[row]);
                s = rsqrtf(deg + 1.0f);
            }
            __hip_bfloat16 hv[4];
            hv[0] = __float2bfloat16(acc[i][0] * s);
            hv[1] = __float2bfloat16(acc[i][1] * s);
            hv[2] = __float2bfloat16(acc[i][2] * s);
            hv[3] = __float2bfloat16(acc[i][3] * s);
            *(ushort4*)&out[(size_t)row * 64 + cg * 4] = *(ushort4*)hv;
        }
    }
}

template<int K>
__global__ void k_gemm_dual(const float* __restrict__ in1, const float* __restrict__ w1,
                            const int* __restrict__ offE, __hip_bfloat16* __restrict__ out1,
                            const float* __restrict__ in2, const float* __restrict__ w2,
                            __hip_bfloat16* __restrict__ out2) {
    __shared__ float wl[64 * 64];
    __shared__ float xs[64 * 68];
    if (blockIdx.x < GG) gemm_body<K, true>(in1, w1, offE, out1, blockIdx.x, wl, xs);
    else                 gemm_body<K, false>(in2, w2, nullptr, out2, blockIdx.x - GG, wl, xs);
}

// ---------------- 2-wide GCN gather body, 8 loads in flight, NT index/output ----------------
template<bool ELU>
__device__ __forceinline__ void gcn_gather_body(const int* __restrict__ off, const int* __restrict__ srcs,
                                                const __hip_bfloat16* __restrict__ xw,
                                                const float* __restrict__ b,
                                                float* __restrict__ out, int blk) {
    int tid = threadIdx.x;
    int wv = tid >> 6, lane = tid & 63;
    int h = lane >> 5, l = lane & 31;
    int wid = blk * 4 + wv;
    if (wid >= N_NODES) return;
    int beg = off[wid];
    int cnt = off[wid + 1] - beg;
    const unsigned* xwu = (const unsigned*)xw;
    float ax0 = 0, ay0 = 0, ax1 = 0, ay1 = 0, ax2 = 0, ay2 = 0, ax3 = 0, ay3 = 0;
    int k = h;
    for (; k + 14 < cnt; k += 16) {
        int s0 = NTL(&srcs[beg + k]),      s1 = NTL(&srcs[beg + k + 2]);
        int s2 = NTL(&srcs[beg + k + 4]),  s3 = NTL(&srcs[beg + k + 6]);
        int s4 = NTL(&srcs[beg + k + 8]),  s5 = NTL(&srcs[beg + k + 10]);
        int s6 = NTL(&srcs[beg + k + 12]), s7 = NTL(&srcs[beg + k + 14]);
        unsigned v0 = xwu[(size_t)s0 * 32 + l];
        unsigned v1 = xwu[(size_t)s1 * 32 + l];
        unsigned v2 = xwu[(size_t)s2 * 32 + l];
        unsigned v3 = xwu[(size_t)s3 * 32 + l];
        unsigned v4 = xwu[(size_t)s4 * 32 + l];
        unsigned v5 = xwu[(size_t)s5 * 32 + l];
        unsigned v6 = xwu[(size_t)s6 * 32 + l];
        unsigned v7 = xwu[(size_t)s7 * 32 + l];
        ax0 += bflo(v0); ay0 += bfhi(v0);
        ax1 += bflo(v1); ay1 += bfhi(v1);
        ax2 += bflo(v2); ay2 += bfhi(v2);
        ax3 += bflo(v3); ay3 += bfhi(v3);
        ax0 += bflo(v4); ay0 += bfhi(v4);
        ax1 += bflo(v5); ay1 += bfhi(v5);
        ax2 += bflo(v6); ay2 += bfhi(v6);
        ax3 += bflo(v7); ay3 += bfhi(v7);
    }
    for (; k + 6 < cnt; k += 8) {
        int s0 = NTL(&srcs[beg + k]),     s1 = NTL(&srcs[beg + k + 2]);
        int s2 = NTL(&srcs[beg + k + 4]), s3 = NTL(&srcs[beg + k + 6]);
        unsigned v0 = xwu[(size_t)s0 * 32 + l];
        unsigned v1 = xwu[(size_t)s1 * 32 + l];
        unsigned v2 = xwu[(size_t)s2 * 32 + l];
        unsigned v3 = xwu[(size_t)s3 * 32 + l];
        ax0 += bflo(v0); ay0 += bfhi(v0);
        ax1 += bflo(v1); ay1 += bfhi(v1);
        ax2 += bflo(v2); ay2 += bfhi(v2);
        ax3 += bflo(v3); ay3 += bfhi(v3);
    }
    for (; k < cnt; k += 2) {
        unsigned v = xwu[(size_t)NTL(&srcs[beg + k]) * 32 + l];
        ax0 += bflo(v); ay0 += bfhi(v);
    }
    float tx = (ax0 + ax1) + (ax2 + ax3);
    float ty = (ay0 + ay1) + (ay2 + ay3);
    tx += __shfl_xor(tx, 32);
    ty += __shfl_xor(ty, 32);
    unsigned sv = xwu[(size_t)wid * 32 + l];
    float di = rsqrtf((float)cnt + 1.0f);
    float vx = di * (tx + bflo(sv)) + b[2 * l];
    float vy = di * (ty + bfhi(sv)) + b[2 * l + 1];
    if (ELU) {
        vx = (vx > 0.0f) ? vx : expm1f(vx);
        vy = (vy > 0.0f) ? vy : expm1f(vy);
    }
    if (h == 0) nts2(out + (size_t)wid * 64 + 2 * l, vx, vy);
}

// ---------------- 2-wide hyperedge gather body, 8 loads in flight ----------------
__device__ __forceinline__ void he_gather_body(const int* __restrict__ off, const int* __restrict__ nodes,
                                               const __hip_bfloat16* __restrict__ xw,
                                               float* __restrict__ C, int he, float2 (*red)[32]) {
    int tid = threadIdx.x;
    int wv = tid >> 6, lane = tid & 63;
    int h = lane >> 5, l = lane & 31;
    int beg = off[he], end = off[he + 1];
    int cnt = end - beg;
    int per = (cnt + 3) >> 2;
    int b0 = beg + wv * per;
    int e0 = min(b0 + per, end);
    int c2 = e0 - b0;
    const unsigned* xwu = (const unsigned*)xw;
    float ax0 = 0, ay0 = 0, ax1 = 0, ay1 = 0, ax2 = 0, ay2 = 0, ax3 = 0, ay3 = 0;
    int k = h;
    for (; k + 14 < c2; k += 16) {
        int s0 = NTL(&nodes[b0 + k]),      s1 = NTL(&nodes[b0 + k + 2]);
        int s2 = NTL(&nodes[b0 + k + 4]),  s3 = NTL(&nodes[b0 + k + 6]);
        int s4 = NTL(&nodes[b0 + k + 8]),  s5 = NTL(&nodes[b0 + k + 10]);
        int s6 = NTL(&nodes[b0 + k + 12]), s7 = NTL(&nodes[b0 + k + 14]);
        unsigned v0 = xwu[(size_t)s0 * 32 + l];
        unsigned v1 = xwu[(size_t)s1 * 32 + l];
        unsigned v2 = xwu[(size_t)s2 * 32 + l];
        unsigned v3 = xwu[(size_t)s3 * 32 + l];
        unsigned v4 = xwu[(size_t)s4 * 32 + l];
        unsigned v5 = xwu[(size_t)s5 * 32 + l];
        unsigned v6 = xwu[(size_t)s6 * 32 + l];
        unsigned v7 = xwu[(size_t)s7 * 32 + l];
        ax0 += bflo(v0); ay0 += bfhi(v0);
        ax1 += bflo(v1); ay1 += bfhi(v1);
        ax2 += bflo(v2); ay2 += bfhi(v2);
        ax3 += bflo(v3); ay3 += bfhi(v3);
        ax0 += bflo(v4); ay0 += bfhi(v4);
        ax1 += bflo(v5); ay1 += bfhi(v5);
        ax2 += bflo(v6); ay2 += bfhi(v6);
        ax3 += bflo(v7); ay3 += bfhi(v7);
    }
    for (; k + 6 < c2; k += 8) {
        int s0 = NTL(&nodes[b0 + k]),     s1 = NTL(&nodes[b0 + k + 2]);
        int s2 = NTL(&nodes[b0 + k + 4]), s3 = NTL(&nodes[b0 + k + 6]);
        unsigned v0 = xwu[(size_t)s0 * 32 + l];
        unsigned v1 = xwu[(size_t)s1 * 32 + l];
        unsigned v2 = xwu[(size_t)s2 * 32 + l];
        unsigned v3 = xwu[(size_t)s3 * 32 + l];
        ax0 += bflo(v0); ay0 += bfhi(v0);
        ax1 += bflo(v1); ay1 += bfhi(v1);
        ax2 += bflo(v2); ay2 += bfhi(v2);
        ax3 += bflo(v3); ay3 += bfhi(v3);
    }
    for (; k < c2; k += 2) {
        unsigned v = xwu[(size_t)NTL(&nodes[b0 + k]) * 32 + l];
        ax0 += bflo(v); ay0 += bfhi(v);
    }
    float tx = (ax0 + ax1) + (ax2 + ax3);
    float ty = (ay0 + ay1) + (ay2 + ay3);
    tx += __shfl_xor(tx, 32);
    ty += __shfl_xor(ty, 32);
    if (h == 0) red[wv][l] = make_float2(tx, ty);
    __syncthreads();
    if (tid < 32) {
        float2 r0 = red[0][tid], r1 = red[1][tid], r2 = red[2][tid], r3 = red[3][tid];
        float binv = (cnt > 0) ? 1.0f / (float)cnt : 0.0f;
        *(float2*)(C + (size_t)he * 64 + 2 * tid) =
            make_float2((r0.x + r1.x + r2.x + r3.x) * binv,
                        (r0.y + r1.y + r2.y + r3.y) * binv);
    }
}

template<bool ELU>
__global__ __launch_bounds__(256, 6)
void k_gather_dual(const int* __restrict__ offE, const int* __restrict__ srtE,
                   const __hip_bfloat16* __restrict__ A, const float* __restrict__ gb,
                   float* __restrict__ aggOut,
                   const int* __restrict__ offH, const int* __restrict__ srtH,
                   const __hip_bfloat16* __restrict__ B, float* __restrict__ C) {
    __shared__ float2 red[4][32];
    if (blockIdx.x < GWN) gcn_gather_body<ELU>(offE, srtE, A, gb, aggOut, blockIdx.x);
    else                  he_gather_body(offH, srtH, B, C, blockIdx.x - GWN, red);
}

// ---------------- 2-wide node gather (fp32 C in): Dinv+bias+ELU (+gating) ----------------
template<bool ELU, bool FUSE>
__global__ __launch_bounds__(256, 8)
void k_node_gather(const int* __restrict__ off, const int* __restrict__ hes,
                   const float* __restrict__ C, const float* __restrict__ b,
                   float* __restrict__ out,
                   const float* __restrict__ xs, const float* __restrict__ gate,
                   float* __restrict__ z) {
    int tid = threadIdx.x;
    int wv = tid >> 6, lane = tid & 63;
    int h = lane >> 5, l = lane & 31;
    int wid = blockIdx.x * 4 + wv;
    if (wid >= N_NODES) return;
    int beg = off[wid];
    int cnt = off[wid + 1] - beg;
    float ax0 = 0, ay0 = 0, ax1 = 0, ay1 = 0, ax2 = 0, ay2 = 0, ax3 = 0, ay3 = 0;
    int k = h;
    for (; k + 6 < cnt; k += 8) {
        int s0 = NTL(&hes[beg + k]),     s1 = NTL(&hes[beg + k + 2]);
        int s2 = NTL(&hes[beg + k + 4]), s3 = NTL(&hes[beg + k + 6]);
        float2 c0 = *(const float2*)(C + (size_t)s0 * 64 + 2 * l);
        float2 c1 = *(const float2*)(C + (size_t)s1 * 64 + 2 * l);
        float2 c2 = *(const float2*)(C + (size_t)s2 * 64 + 2 * l);
        float2 c3 = *(const float2*)(C + (size_t)s3 * 64 + 2 * l);
        ax0 += c0.x; ay0 += c0.y;
        ax1 += c1.x; ay1 += c1.y;
        ax2 += c2.x; ay2 += c2.y;
        ax3 += c3.x; ay3 += c3.y;
    }
    for (; k < cnt; k += 2) {
        float2 c = *(const float2*)(C + (size_t)NTL(&hes[beg + k]) * 64 + 2 * l);
        ax0 += c.x; ay0 += c.y;
    }
    float tx = (ax0 + ax1) + (ax2 + ax3);
    float ty = (ay0 + ay1) + (ay2 + ay3);
    tx += __shfl_xor(tx, 32);
    ty += __shfl_xor(ty, 32);
    float dinv = (cnt > 0) ? 1.0f / (float)cnt : 0.0f;
    float vx = dinv * tx + b[2 * l];
    float vy = dinv * ty + b[2 * l + 1];
    if (ELU) {
        vx = (vx > 0.0f) ? vx : expm1f(vx);
        vy = (vy > 0.0f) ? vy : expm1f(vy);
    }
    if (h == 0) {
        size_t idx = (size_t)wid * 64 + 2 * l;
        nts2(out + idx, vx, vy);
        if (FUSE) {
            float a = 1.0f / (1.0f + expf(-gate[0]));
            float2 s = *(const float2*)(xs + idx);
            nts2(z + idx, a * s.x + (1.0f - a) * vx, a * s.y + (1.0f - a) * vy);
        }
    }
}

extern "C" void kernel_launch(void* const* d_in, const int* in_sizes, int n_in,
                              void* d_out, int out_size, void* d_ws, size_t ws_size,
                              hipStream_t stream) {
    const float* x      = (const float*)d_in[0];
    const int*   ei     = (const int*)d_in[1];
    const int*   hei    = (const int*)d_in[2];
    const float* gcn1_w = (const float*)d_in[3];
    const float* gcn1_b = (const float*)d_in[4];
    const float* gcn2_w = (const float*)d_in[5];
    const float* gcn2_b = (const float*)d_in[6];
    const float* hyp1_w = (const float*)d_in[7];
    const float* hyp1_b = (const float*)d_in[8];
    const float* hyp2_w = (const float*)d_in[9];
    const float* hyp2_b = (const float*)d_in[10];
    const float* gate   = (const float*)d_in[11];
    float* out = (float*)d_out;

    const int* e_row = ei;
    const int* e_col = ei + N_EDGES;
    const int* n_idx = hei;
    const int* h_idx = hei + NNZ_H;

    const size_t NV = (size_t)N_NODES * 64;
    float* z_out  = out;
    float* xs_out = out + NV;
    float* xd_out = out + 2 * NV;

    // ---- workspace layout ----
    char* base = (char*)d_ws;
    __hip_bfloat16* Abf = (__hip_bfloat16*)base;            // 6.4 MB
    __hip_bfloat16* Bbf = (__hip_bfloat16*)(base + NV * 2); // 6.4 MB
    float* AGG1 = (float*)(base + NV * 4);                  // 12.8 MB
    float* AGG2 = (float*)(base + NV * 8);                  // 12.8 MB
    float* C    = (float*)(base + NV * 12);                 // 2.56 MB
    int* srtE = (int*)(C + (size_t)M_HE * 64);
    int* srtH = srtE + N_EDGES;
    int* srtN = srtH + NNZ_H;
    int* offE = srtN + NNZ_H;
    int* offH = offE + (N_NODES + 1);
    int* offN = offH + (M_HE + 1);
    int* bcntE = offN + (N_NODES + 1);
    int* bcntH = bcntE + NB_E;
    int* bcntN = bcntH + NB_H;
    int* bcurE = bcntN + NB_N;
    int* bcurH = bcurE + NB_E;
    int* bcurN = bcurH + NB_H;
    const size_t zero_ints = 2 * (size_t)(NB_E + NB_H + NB_N);
    int* bkE = (int*)Abf;
    int* bkH = (int*)Bbf;
    int* bkN = (int*)AGG1;

    const int BLK = 256;

    // ---- CSR build (3 launches) ----
    hipMemsetAsync(bcntE, 0, zero_ints * sizeof(int), stream);
    k_hist_all<<<256, BLK, 0, stream>>>(e_col, h_idx, n_idx, bcntE, bcntH, bcntN);
    k_chunk_all<<<3 * GB, BLK, 0, stream>>>(e_row, e_col, n_idx, h_idx,
                                            bcntE, bcurE, bkE,
                                            bcntH, bcurH, bkH,
                                            bcntN, bcurN, bkN);
    k_fin_all<<<NB_E + NB_H + NB_N, BLK, 0, stream>>>(bkE, bcntE, srtE, offE,
                                                      bkH, bcntH, srtH, offH,
                                                      bkN, bcntN, srtN, offN);

    // ---- G13: Abf = dis.*(x@w1)  ||  Bbf = x@hw1 ----
    k_gemm_dual<F_IN><<<2 * GG, BLK, 0, stream>>>(x, gcn1_w, offE, Abf, x, hyp1_w, Bbf);
    // ---- DG1: AGG1 = ELU(gcnGather(Abf))  ||  C = heGather(Bbf) ----
    k_gather_dual<true><<<GWN + M_HE, BLK, 0, stream>>>(offE, srtE, Abf, gcn1_b, AGG1,
                                                        offH, srtH, Bbf, C);
    // ---- nodeG1: AGG2 = ELU(Dinv*(H C) + hb1) ----
    k_node_gather<true, false><<<GWN, BLK, 0, stream>>>(offN, srtN, C, hyp1_b, AGG2,
                                                        nullptr, nullptr, nullptr);
    // ---- G24: Abf = dis.*(AGG1@w2)  ||  Bbf = AGG2@hw2 ----
    k_gemm_dual<F_HID><<<2 * GG, BLK, 0, stream>>>(AGG1, gcn2_w, offE, Abf, AGG2, hyp2_w, Bbf);
    // ---- DG2: xs_out = gcnGather(Abf)  ||  C = heGather(Bbf) ----
    k_gather_dual<false><<<GWN + M_HE, BLK, 0, stream>>>(offE, srtE, Abf, gcn2_b, xs_out,
                                                         offH, srtH, Bbf, C);
    // ---- nodeG2 + gating ----
    k_node_gather<false, true><<<GWN, BLK, 0, stream>>>(offN, srtN, C, hyp2_b, xd_out,
                                                        xs_out, gate, z_out);

    (void)in_sizes; (void)n_in; (void)out_size; (void)ws_size;
}

// Round 16
// 259.897 us; speedup vs baseline: 1.1572x; 1.1572x over previous
//
#include <hip/hip_runtime.h>
#include <hip/hip_bf16.h>

#define N_NODES 50000
#define N_EDGES 800000
#define NNZ_H   800000
#define M_HE    10000
#define F_IN    128
#define F_HID   64

// coarse-bucket geometry for the two-level counting sort
#define SH_E 7
#define NB_E ((N_NODES + 127) >> 7)     // 391
#define SH_H 5
#define NB_H ((M_HE + 31) >> 5)         // 313
#define SH_N 7
#define NB_N ((N_NODES + 127) >> 7)     // 391
#define TILE 4096
#define GB   ((N_EDGES + TILE - 1) / TILE)   // 196 (E == NNZ)
#define NBMAX 400
#define KPBMAX 128
#define GG  782     // (N_NODES+63)/64 GEMM blocks
#define GWN 12500   // N_NODES/4 wave-per-node blocks

static __device__ __forceinline__ float bflo(unsigned v) { return __uint_as_float(v << 16); }
static __device__ __forceinline__ float bfhi(unsigned v) { return __uint_as_float(v & 0xFFFF0000u); }

// ---------------- pass A: fused bucket histograms (int2 reads) ----------------
__global__ void k_hist_all(const int* __restrict__ e_col, const int* __restrict__ h_idx,
                           const int* __restrict__ n_idx,
                           int* __restrict__ bcntE, int* __restrict__ bcntH, int* __restrict__ bcntN) {
    __shared__ int hE[NB_E], hH[NB_H], hN[NB_N];
    for (int i = threadIdx.x; i < NB_E; i += 256) hE[i] = 0;
    for (int i = threadIdx.x; i < NB_H; i += 256) hH[i] = 0;
    for (int i = threadIdx.x; i < NB_N; i += 256) hN[i] = 0;
    __syncthreads();
    const int2* ec2 = (const int2*)e_col;
    const int2* hi2 = (const int2*)h_idx;
    const int2* ni2 = (const int2*)n_idx;
    int stride = gridDim.x * 256;
    for (int i = blockIdx.x * 256 + threadIdx.x; i < N_EDGES / 2; i += stride) {
        int2 e = ec2[i];
        atomicAdd(&hE[e.x >> SH_E], 1);
        atomicAdd(&hE[e.y >> SH_E], 1);
        int2 hh = hi2[i];
        atomicAdd(&hH[hh.x >> SH_H], 1);
        atomicAdd(&hH[hh.y >> SH_H], 1);
        int2 nn = ni2[i];
        atomicAdd(&hN[nn.x >> SH_N], 1);
        atomicAdd(&hN[nn.y >> SH_N], 1);
    }
    __syncthreads();
    for (int i = threadIdx.x; i < NB_E; i += 256) if (hE[i]) atomicAdd(&bcntE[i], hE[i]);
    for (int i = threadIdx.x; i < NB_H; i += 256) if (hH[i]) atomicAdd(&bcntH[i], hH[i]);
    for (int i = threadIdx.x; i < NB_N; i += 256) if (hN[i]) atomicAdd(&bcntN[i], hN[i]);
}

// ---------------- in-LDS exclusive scan of bcnt[0..nb) (nb <= 512), 256 threads ----------------
__device__ void scan_to_lds(const int* __restrict__ in, int* __restrict__ soff, int nb,
                            int* __restrict__ tsum) {
    int t = threadIdx.x;
    int v0 = (2 * t < nb) ? in[2 * t] : 0;
    int v1 = (2 * t + 1 < nb) ? in[2 * t + 1] : 0;
    tsum[t] = v0 + v1;
    __syncthreads();
    for (int d = 1; d < 256; d <<= 1) {
        int u = (t >= d) ? tsum[t - d] : 0;
        __syncthreads();
        tsum[t] += u;
        __syncthreads();
    }
    int run = (t > 0) ? tsum[t - 1] : 0;
    if (2 * t < nb) soff[2 * t] = run;
    if (2 * t + 1 < nb) soff[2 * t + 1] = run + v0;
    __syncthreads();
}

// ---------------- pass B: chunked scatter, packed payload, self-scanned offsets ----------------
__device__ void chunk_scatter(const int* __restrict__ keys, const int* __restrict__ vals,
                              int n, int sh, int nb,
                              const int* __restrict__ bcnt, int* __restrict__ bcur,
                              int* __restrict__ bk, int blk) {
    __shared__ int h[NBMAX], loc[NBMAX], base[NBMAX], hc[NBMAX], soff[NBMAX];
    __shared__ int tsum[256];
    __shared__ int buf[TILE];
    __shared__ unsigned short bkt[TILE];
    scan_to_lds(bcnt, soff, nb, tsum);
    int t0 = blk * TILE;
    int tend = min(t0 + TILE, n);
    int cnt = tend - t0;
    for (int b = threadIdx.x; b < nb; b += 256) { h[b] = 0; hc[b] = 0; }
    __syncthreads();
    for (int i = t0 + threadIdx.x; i < tend; i += 256)
        atomicAdd(&h[keys[i] >> sh], 1);
    __syncthreads();
    if (threadIdx.x == 0) {
        int run = 0;
        for (int b = 0; b < nb; ++b) { loc[b] = run; run += h[b]; }
    }
    __syncthreads();
    for (int b = threadIdx.x; b < nb; b += 256)
        base[b] = soff[b] + atomicAdd(&bcur[b], h[b]);
    __syncthreads();
    for (int i = t0 + threadIdx.x; i < tend; i += 256) {
        int k = keys[i];
        int b = k >> sh;
        int r = loc[b] + atomicAdd(&hc[b], 1);
        buf[r] = ((k - (b << sh)) << 16) | vals[i];
        bkt[r] = (unsigned short)b;
    }
    __syncthreads();
    for (int j = threadIdx.x; j < cnt; j += 256) {
        int b = bkt[j];
        bk[base[b] + (j - loc[b])] = buf[j];
    }
}
__global__ void k_chunk_all(const int* __restrict__ e_row, const int* __restrict__ e_col,
                            const int* __restrict__ n_idx, const int* __restrict__ h_idx,
                            const int* __restrict__ bcntE, int* __restrict__ bcurE, int* __restrict__ bkE,
                            const int* __restrict__ bcntH, int* __restrict__ bcurH, int* __restrict__ bkH,
                            const int* __restrict__ bcntN, int* __restrict__ bcurN, int* __restrict__ bkN) {
    int gb = blockIdx.x;
    if (gb < GB)            chunk_scatter(e_col, e_row, N_EDGES, SH_E, NB_E, bcntE, bcurE, bkE, gb);
    else if (gb < 2 * GB)   chunk_scatter(h_idx, n_idx, NNZ_H,  SH_H, NB_H, bcntH, bcurH, bkH, gb - GB);
    else                    chunk_scatter(n_idx, h_idx, NNZ_H,  SH_N, NB_N, bcntN, bcurN, bkN, gb - 2 * GB);
}

// ---------------- pass C: per-bucket CSR finalize, self-scanned offsets ----------------
__global__ void k_fin_all(const int* __restrict__ bkE, const int* __restrict__ bcntE,
                          int* __restrict__ srtE, int* __restrict__ offE,
                          const int* __restrict__ bkH, const int* __restrict__ bcntH,
                          int* __restrict__ srtH, int* __restrict__ offH,
                          const int* __restrict__ bkN, const int* __restrict__ bcntN,
                          int* __restrict__ srtN, int* __restrict__ offN) {
    __shared__ int koff[KPBMAX];
    __shared__ int kcur[KPBMAX];
    __shared__ int tsum[256];
    __shared__ int soff[NBMAX];
    int b = blockIdx.x;
    const int* bk; const int* bcnt; int* srt; int* off;
    int nb, sh, nkeys, total;
    if (b < NB_E) {
        bk = bkE; bcnt = bcntE; srt = srtE; off = offE;
        nb = NB_E; sh = SH_E; nkeys = N_NODES; total = N_EDGES;
    } else if (b < NB_E + NB_H) {
        b -= NB_E;
        bk = bkH; bcnt = bcntH; srt = srtH; off = offH;
        nb = NB_H; sh = SH_H; nkeys = M_HE; total = NNZ_H;
    } else {
        b -= NB_E + NB_H;
        bk = bkN; bcnt = bcntN; srt = srtN; off = offN;
        nb = NB_N; sh = SH_N; nkeys = N_NODES; total = NNZ_H;
    }
    scan_to_lds(bcnt, soff, nb, tsum);
    int kpb = 1 << sh;
    int k0 = b << sh;
    int beg = soff[b];
    int end = (b + 1 < nb) ? soff[b + 1] : total;
    int t = threadIdx.x;
    if (t < kpb) { koff[t] = 0; kcur[t] = 0; }
    __syncthreads();
    for (int i = beg + t; i < end; i += 256)
        atomicAdd(&koff[((unsigned)bk[i]) >> 16], 1);
    __syncthreads();
    int v = (t < kpb) ? koff[t] : 0;
    tsum[t] = v;
    __syncthreads();
    for (int d = 1; d < 256; d <<= 1) {
        int u = (t >= d) ? tsum[t - d] : 0;
        __syncthreads();
        tsum[t] += u;
        __syncthreads();
    }
    if (t < kpb) koff[t] = tsum[t] - v;
    __syncthreads();
    if (t < kpb && (k0 + t) < nkeys) off[k0 + t] = beg + koff[t];
    if (b == nb - 1 && t == 0) off[nkeys] = total;
    for (int i = beg + t; i < end; i += 256) {
        int p = bk[i];
        int lk = ((unsigned)p) >> 16;
        int pos = beg + koff[lk] + atomicAdd(&kcur[lk], 1);
        srt[pos] = p & 0xFFFF;
    }
}

// ---------------- register-tiled GEMM body -> bf16 out ----------------
template<int K, bool SCALE>
__device__ __forceinline__ void gemm_body(const float* __restrict__ xin, const float* __restrict__ w,
                                          const int* __restrict__ offE, __hip_bfloat16* __restrict__ out,
                                          int blk, float* __restrict__ wl, float* __restrict__ xs) {
    int tid = threadIdx.x;
    int wv = tid >> 6, lane = tid & 63;
    int cg = lane & 15;
    int rg = lane >> 4;
    int rl = wv * 16 + rg * 4;
    int r0 = blk * 64;
    float acc[4][4] = {};
    for (int k0 = 0; k0 < K; k0 += 64) {
        {
            const float4* wsrc = (const float4*)(w + k0 * 64);
            float4* wdst = (float4*)wl;
            for (int j = tid; j < 1024; j += 256) wdst[j] = wsrc[j];
        }
        for (int p = tid; p < 1024; p += 256) {
            int r = p >> 4, c4 = p & 15;
            int row = min(r0 + r, N_NODES - 1);
            float4 vv = *(const float4*)(xin + (size_t)row * K + k0 + 4 * c4);
            *(float4*)&xs[r * 68 + 4 * c4] = vv;
        }
        __syncthreads();
#pragma unroll 4
        for (int kk = 0; kk < 64; ++kk) {
            float4 wf = *(const float4*)&wl[kk * 64 + cg * 4];
            float x0 = xs[(rl + 0) * 68 + kk];
            float x1 = xs[(rl + 1) * 68 + kk];
            float x2 = xs[(rl + 2) * 68 + kk];
            float x3 = xs[(rl + 3) * 68 + kk];
            acc[0][0] += x0 * wf.x; acc[0][1] += x0 * wf.y; acc[0][2] += x0 * wf.z; acc[0][3] += x0 * wf.w;
            acc[1][0] += x1 * wf.x; acc[1][1] += x1 * wf.y; acc[1][2] += x1 * wf.z; acc[1][3] += x1 * wf.w;
            acc[2][0] += x2 * wf.x; acc[2][1] += x2 * wf.y; acc[2][2] += x2 * wf.z; acc[2][3] += x2 * wf.w;
            acc[3][0] += x3 * wf.x; acc[3][1] += x3 * wf.y; acc[3][2] += x3 * wf.z; acc[3][3] += x3 * wf.w;
        }
        __syncthreads();
    }
#pragma unroll
    for (int i = 0; i < 4; ++i) {
        int row = r0 + rl + i;
        if (row < N_NODES) {
            float s = 1.0f;
            if (SCALE) {
                float deg = (float)(offE[row + 1] - offE[row]);
                s = rsqrtf(deg + 1.0f);
            }
            __hip_bfloat16 hv[4];
            hv[0] = __float2bfloat16(acc[i][0] * s);
            hv[1] = __float2bfloat16(acc[i][1] * s);
            hv[2] = __float2bfloat16(acc[i][2] * s);
            hv[3] = __float2bfloat16(acc[i][3] * s);
            *(ushort4*)&out[(size_t)row * 64 + cg * 4] = *(ushort4*)hv;
        }
    }
}

template<int K>
__global__ void k_gemm_dual(const float* __restrict__ in1, const float* __restrict__ w1,
                            const int* __restrict__ offE, __hip_bfloat16* __restrict__ out1,
                            const float* __restrict__ in2, const float* __restrict__ w2,
                            __hip_bfloat16* __restrict__ out2) {
    __shared__ float wl[64 * 64];
    __shared__ float xs[64 * 68];
    if (blockIdx.x < GG) gemm_body<K, true>(in1, w1, offE, out1, blockIdx.x, wl, xs);
    else                 gemm_body<K, false>(in2, w2, nullptr, out2, blockIdx.x - GG, wl, xs);
}

// ---------------- 2-wide GCN gather body, 8 loads in flight ----------------
template<bool ELU>
__device__ __forceinline__ void gcn_gather_body(const int* __restrict__ off, const int* __restrict__ srcs,
                                                const __hip_bfloat16* __restrict__ xw,
                                                const float* __restrict__ b,
                                                float* __restrict__ out, int blk) {
    int tid = threadIdx.x;
    int wv = tid >> 6, lane = tid & 63;
    int h = lane >> 5, l = lane & 31;
    int wid = blk * 4 + wv;
    if (wid >= N_NODES) return;
    int beg = off[wid];
    int cnt = off[wid + 1] - beg;
    const unsigned* xwu = (const unsigned*)xw;
    float ax0 = 0, ay0 = 0, ax1 = 0, ay1 = 0, ax2 = 0, ay2 = 0, ax3 = 0, ay3 = 0;
    int k = h;
    for (; k + 14 < cnt; k += 16) {
        int s0 = srcs[beg + k],      s1 = srcs[beg + k + 2];
        int s2 = srcs[beg + k + 4],  s3 = srcs[beg + k + 6];
        int s4 = srcs[beg + k + 8],  s5 = srcs[beg + k + 10];
        int s6 = srcs[beg + k + 12], s7 = srcs[beg + k + 14];
        unsigned v0 = xwu[(size_t)s0 * 32 + l];
        unsigned v1 = xwu[(size_t)s1 * 32 + l];
        unsigned v2 = xwu[(size_t)s2 * 32 + l];
        unsigned v3 = xwu[(size_t)s3 * 32 + l];
        unsigned v4 = xwu[(size_t)s4 * 32 + l];
        unsigned v5 = xwu[(size_t)s5 * 32 + l];
        unsigned v6 = xwu[(size_t)s6 * 32 + l];
        unsigned v7 = xwu[(size_t)s7 * 32 + l];
        ax0 += bflo(v0); ay0 += bfhi(v0);
        ax1 += bflo(v1); ay1 += bfhi(v1);
        ax2 += bflo(v2); ay2 += bfhi(v2);
        ax3 += bflo(v3); ay3 += bfhi(v3);
        ax0 += bflo(v4); ay0 += bfhi(v4);
        ax1 += bflo(v5); ay1 += bfhi(v5);
        ax2 += bflo(v6); ay2 += bfhi(v6);
        ax3 += bflo(v7); ay3 += bfhi(v7);
    }
    for (; k + 6 < cnt; k += 8) {
        int s0 = srcs[beg + k],     s1 = srcs[beg + k + 2];
        int s2 = srcs[beg + k + 4], s3 = srcs[beg + k + 6];
        unsigned v0 = xwu[(size_t)s0 * 32 + l];
        unsigned v1 = xwu[(size_t)s1 * 32 + l];
        unsigned v2 = xwu[(size_t)s2 * 32 + l];
        unsigned v3 = xwu[(size_t)s3 * 32 + l];
        ax0 += bflo(v0); ay0 += bfhi(v0);
        ax1 += bflo(v1); ay1 += bfhi(v1);
        ax2 += bflo(v2); ay2 += bfhi(v2);
        ax3 += bflo(v3); ay3 += bfhi(v3);
    }
    for (; k < cnt; k += 2) {
        unsigned v = xwu[(size_t)srcs[beg + k] * 32 + l];
        ax0 += bflo(v); ay0 += bfhi(v);
    }
    float tx = (ax0 + ax1) + (ax2 + ax3);
    float ty = (ay0 + ay1) + (ay2 + ay3);
    tx += __shfl_xor(tx, 32);
    ty += __shfl_xor(ty, 32);
    unsigned sv = xwu[(size_t)wid * 32 + l];
    float di = rsqrtf((float)cnt + 1.0f);
    float vx = di * (tx + bflo(sv)) + b[2 * l];
    float vy = di * (ty + bfhi(sv)) + b[2 * l + 1];
    if (ELU) {
        vx = (vx > 0.0f) ? vx : expm1f(vx);
        vy = (vy > 0.0f) ? vy : expm1f(vy);
    }
    if (h == 0) *(float2*)(out + (size_t)wid * 64 + 2 * l) = make_float2(vx, vy);
}

// ---------------- 2-wide hyperedge gather body, 8 loads in flight ----------------
__device__ __forceinline__ void he_gather_body(const int* __restrict__ off, const int* __restrict__ nodes,
                                               const __hip_bfloat16* __restrict__ xw,
                                               float* __restrict__ C, int he, float2 (*red)[32]) {
    int tid = threadIdx.x;
    int wv = tid >> 6, lane = tid & 63;
    int h = lane >> 5, l = lane & 31;
    int beg = off[he], end = off[he + 1];
    int cnt = end - beg;
    int per = (cnt + 3) >> 2;
    int b0 = beg + wv * per;
    int e0 = min(b0 + per, end);
    int c2 = e0 - b0;
    const unsigned* xwu = (const unsigned*)xw;
    float ax0 = 0, ay0 = 0, ax1 = 0, ay1 = 0, ax2 = 0, ay2 = 0, ax3 = 0, ay3 = 0;
    int k = h;
    for (; k + 14 < c2; k += 16) {
        int s0 = nodes[b0 + k],      s1 = nodes[b0 + k + 2];
        int s2 = nodes[b0 + k + 4],  s3 = nodes[b0 + k + 6];
        int s4 = nodes[b0 + k + 8],  s5 = nodes[b0 + k + 10];
        int s6 = nodes[b0 + k + 12], s7 = nodes[b0 + k + 14];
        unsigned v0 = xwu[(size_t)s0 * 32 + l];
        unsigned v1 = xwu[(size_t)s1 * 32 + l];
        unsigned v2 = xwu[(size_t)s2 * 32 + l];
        unsigned v3 = xwu[(size_t)s3 * 32 + l];
        unsigned v4 = xwu[(size_t)s4 * 32 + l];
        unsigned v5 = xwu[(size_t)s5 * 32 + l];
        unsigned v6 = xwu[(size_t)s6 * 32 + l];
        unsigned v7 = xwu[(size_t)s7 * 32 + l];
        ax0 += bflo(v0); ay0 += bfhi(v0);
        ax1 += bflo(v1); ay1 += bfhi(v1);
        ax2 += bflo(v2); ay2 += bfhi(v2);
        ax3 += bflo(v3); ay3 += bfhi(v3);
        ax0 += bflo(v4); ay0 += bfhi(v4);
        ax1 += bflo(v5); ay1 += bfhi(v5);
        ax2 += bflo(v6); ay2 += bfhi(v6);
        ax3 += bflo(v7); ay3 += bfhi(v7);
    }
    for (; k + 6 < c2; k += 8) {
        int s0 = nodes[b0 + k],     s1 = nodes[b0 + k + 2];
        int s2 = nodes[b0 + k + 4], s3 = nodes[b0 + k + 6];
        unsigned v0 = xwu[(size_t)s0 * 32 + l];
        unsigned v1 = xwu[(size_t)s1 * 32 + l];
        unsigned v2 = xwu[(size_t)s2 * 32 + l];
        unsigned v3 = xwu[(size_t)s3 * 32 + l];
        ax0 += bflo(v0); ay0 += bfhi(v0);
        ax1 += bflo(v1); ay1 += bfhi(v1);
        ax2 += bflo(v2); ay2 += bfhi(v2);
        ax3 += bflo(v3); ay3 += bfhi(v3);
    }
    for (; k < c2; k += 2) {
        unsigned v = xwu[(size_t)nodes[b0 + k] * 32 + l];
        ax0 += bflo(v); ay0 += bfhi(v);
    }
    float tx = (ax0 + ax1) + (ax2 + ax3);
    float ty = (ay0 + ay1) + (ay2 + ay3);
    tx += __shfl_xor(tx, 32);
    ty += __shfl_xor(ty, 32);
    if (h == 0) red[wv][l] = make_float2(tx, ty);
    __syncthreads();
    if (tid < 32) {
        float2 r0 = red[0][tid], r1 = red[1][tid], r2 = red[2][tid], r3 = red[3][tid];
        float binv = (cnt > 0) ? 1.0f / (float)cnt : 0.0f;
        *(float2*)(C + (size_t)he * 64 + 2 * tid) =
            make_float2((r0.x + r1.x + r2.x + r3.x) * binv,
                        (r0.y + r1.y + r2.y + r3.y) * binv);
    }
}

template<bool ELU>
__global__ __launch_bounds__(256, 6)
void k_gather_dual(const int* __restrict__ offE, const int* __restrict__ srtE,
                   const __hip_bfloat16* __restrict__ A, const float* __restrict__ gb,
                   float* __restrict__ aggOut,
                   const int* __restrict__ offH, const int* __restrict__ srtH,
                   const __hip_bfloat16* __restrict__ B, float* __restrict__ C) {
    __shared__ float2 red[4][32];
    if (blockIdx.x < GWN) gcn_gather_body<ELU>(offE, srtE, A, gb, aggOut, blockIdx.x);
    else                  he_gather_body(offH, srtH, B, C, blockIdx.x - GWN, red);
}

// ---------------- 2-wide node gather (fp32 C in): Dinv+bias+ELU (+gating) ----------------
template<bool ELU, bool FUSE>
__global__ __launch_bounds__(256, 8)
void k_node_gather(const int* __restrict__ off, const int* __restrict__ hes,
                   const float* __restrict__ C, const float* __restrict__ b,
                   float* __restrict__ out,
                   const float* __restrict__ xs, const float* __restrict__ gate,
                   float* __restrict__ z) {
    int tid = threadIdx.x;
    int wv = tid >> 6, lane = tid & 63;
    int h = lane >> 5, l = lane & 31;
    int wid = blockIdx.x * 4 + wv;
    if (wid >= N_NODES) return;
    int beg = off[wid];
    int cnt = off[wid + 1] - beg;
    float ax0 = 0, ay0 = 0, ax1 = 0, ay1 = 0, ax2 = 0, ay2 = 0, ax3 = 0, ay3 = 0;
    int k = h;
    for (; k + 6 < cnt; k += 8) {
        float2 c0 = *(const float2*)(C + (size_t)hes[beg + k] * 64 + 2 * l);
        float2 c1 = *(const float2*)(C + (size_t)hes[beg + k + 2] * 64 + 2 * l);
        float2 c2 = *(const float2*)(C + (size_t)hes[beg + k + 4] * 64 + 2 * l);
        float2 c3 = *(const float2*)(C + (size_t)hes[beg + k + 6] * 64 + 2 * l);
        ax0 += c0.x; ay0 += c0.y;
        ax1 += c1.x; ay1 += c1.y;
        ax2 += c2.x; ay2 += c2.y;
        ax3 += c3.x; ay3 += c3.y;
    }
    for (; k < cnt; k += 2) {
        float2 c = *(const float2*)(C + (size_t)hes[beg + k] * 64 + 2 * l);
        ax0 += c.x; ay0 += c.y;
    }
    float tx = (ax0 + ax1) + (ax2 + ax3);
    float ty = (ay0 + ay1) + (ay2 + ay3);
    tx += __shfl_xor(tx, 32);
    ty += __shfl_xor(ty, 32);
    float dinv = (cnt > 0) ? 1.0f / (float)cnt : 0.0f;
    float vx = dinv * tx + b[2 * l];
    float vy = dinv * ty + b[2 * l + 1];
    if (ELU) {
        vx = (vx > 0.0f) ? vx : expm1f(vx);
        vy = (vy > 0.0f) ? vy : expm1f(vy);
    }
    if (h == 0) {
        size_t idx = (size_t)wid * 64 + 2 * l;
        *(float2*)(out + idx) = make_float2(vx, vy);
        if (FUSE) {
            float a = 1.0f / (1.0f + expf(-gate[0]));
            float2 s = *(const float2*)(xs + idx);
            *(float2*)(z + idx) = make_float2(a * s.x + (1.0f - a) * vx,
                                              a * s.y + (1.0f - a) * vy);
        }
    }
}

extern "C" void kernel_launch(void* const* d_in, const int* in_sizes, int n_in,
                              void* d_out, int out_size, void* d_ws, size_t ws_size,
                              hipStream_t stream) {
    const float* x      = (const float*)d_in[0];
    const int*   ei     = (const int*)d_in[1];
    const int*   hei    = (const int*)d_in[2];
    const float* gcn1_w = (const float*)d_in[3];
    const float* gcn1_b = (const float*)d_in[4];
    const float* gcn2_w = (const float*)d_in[5];
    const float* gcn2_b = (const float*)d_in[6];
    const float* hyp1_w = (const float*)d_in[7];
    const float* hyp1_b = (const float*)d_in[8];
    const float* hyp2_w = (const float*)d_in[9];
    const float* hyp2_b = (const float*)d_in[10];
    const float* gate   = (const float*)d_in[11];
    float* out = (float*)d_out;

    const int* e_row = ei;
    const int* e_col = ei + N_EDGES;
    const int* n_idx = hei;
    const int* h_idx = hei + NNZ_H;

    const size_t NV = (size_t)N_NODES * 64;
    float* z_out  = out;
    float* xs_out = out + NV;
    float* xd_out = out + 2 * NV;

    // ---- workspace layout ----
    char* base = (char*)d_ws;
    __hip_bfloat16* Abf = (__hip_bfloat16*)base;            // 6.4 MB
    __hip_bfloat16* Bbf = (__hip_bfloat16*)(base + NV * 2); // 6.4 MB
    float* AGG1 = (float*)(base + NV * 4);                  // 12.8 MB
    float* AGG2 = (float*)(base + NV * 8);                  // 12.8 MB
    float* C    = (float*)(base + NV * 12);                 // 2.56 MB
    int* srtE = (int*)(C + (size_t)M_HE * 64);
    int* srtH = srtE + N_EDGES;
    int* srtN = srtH + NNZ_H;
    int* offE = srtN + NNZ_H;
    int* offH = offE + (N_NODES + 1);
    int* offN = offH + (M_HE + 1);
    int* bcntE = offN + (N_NODES + 1);
    int* bcntH = bcntE + NB_E;
    int* bcntN = bcntH + NB_H;
    int* bcurE = bcntN + NB_N;
    int* bcurH = bcurE + NB_E;
    int* bcurN = bcurH + NB_H;
    const size_t zero_ints = 2 * (size_t)(NB_E + NB_H + NB_N);
    int* bkE = (int*)Abf;
    int* bkH = (int*)Bbf;
    int* bkN = (int*)AGG1;

    const int BLK = 256;

    // ---- CSR build (3 launches) ----
    hipMemsetAsync(bcntE, 0, zero_ints * sizeof(int), stream);
    k_hist_all<<<256, BLK, 0, stream>>>(e_col, h_idx, n_idx, bcntE, bcntH, bcntN);
    k_chunk_all<<<3 * GB, BLK, 0, stream>>>(e_row, e_col, n_idx, h_idx,
                                            bcntE, bcurE, bkE,
                                            bcntH, bcurH, bkH,
                                            bcntN, bcurN, bkN);
    k_fin_all<<<NB_E + NB_H + NB_N, BLK, 0, stream>>>(bkE, bcntE, srtE, offE,
                                                      bkH, bcntH, srtH, offH,
                                                      bkN, bcntN, srtN, offN);

    // ---- G13: Abf = dis.*(x@w1)  ||  Bbf = x@hw1 ----
    k_gemm_dual<F_IN><<<2 * GG, BLK, 0, stream>>>(x, gcn1_w, offE, Abf, x, hyp1_w, Bbf);
    // ---- DG1: AGG1 = ELU(gcnGather(Abf))  ||  C = heGather(Bbf) ----
    k_gather_dual<true><<<GWN + M_HE, BLK, 0, stream>>>(offE, srtE, Abf, gcn1_b, AGG1,
                                                        offH, srtH, Bbf, C);
    // ---- nodeG1: AGG2 = ELU(Dinv*(H C) + hb1) ----
    k_node_gather<true, false><<<GWN, BLK, 0, stream>>>(offN, srtN, C, hyp1_b, AGG2,
                                                        nullptr, nullptr, nullptr);
    // ---- G24: Abf = dis.*(AGG1@w2)  ||  Bbf = AGG2@hw2 ----
    k_gemm_dual<F_HID><<<2 * GG, BLK, 0, stream>>>(AGG1, gcn2_w, offE, Abf, AGG2, hyp2_w, Bbf);
    // ---- DG2: xs_out = gcnGather(Abf)  ||  C = heGather(Bbf) ----
    k_gather_dual<false><<<GWN + M_HE, BLK, 0, stream>>>(offE, srtE, Abf, gcn2_b, xs_out,
                                                         offH, srtH, Bbf, C);
    // ---- nodeG2 + gating ----
    k_node_gather<false, true><<<GWN, BLK, 0, stream>>>(offN, srtN, C, hyp2_b, xd_out,
                                                        xs_out, gate, z_out);

    (void)in_sizes; (void)n_in; (void)out_size; (void)ws_size;
}